// Round 7
// baseline (379.449 us; speedup 1.0000x reference)
//
#include <hip/hip_runtime.h>
#include <cstdint>
#include <cstddef>

#define DMODEL 1024
#define DH 2048
#define BATCH 2
#define SEQ 4096
#define MROWS (BATCH*SEQ)    // 8192
#define CHUNK 64
#define NCHUNK (SEQ/CHUNK)   // 64

typedef unsigned short u16;
typedef __attribute__((ext_vector_type(8))) short bf16x8;
typedef __attribute__((ext_vector_type(4))) float f32x4;

__device__ __forceinline__ u16 f2bf(float f) {
    union { float f; unsigned u; } v; v.f = f;
    unsigned r = v.u + 0x7FFFu + ((v.u >> 16) & 1u);
    return (u16)(r >> 16);
}
__device__ __forceinline__ float bf2f(u16 h) {
    union { unsigned u; float f; } v; v.u = ((unsigned)h) << 16; return v.f;
}

// fast softplus: for x < -4, softplus(x) = log1p(e^x) ≈ e^x (rel err ≤ e^-4/2 ≈ 0.9%,
// typical x≈-8 → 1.7e-4). Exact branches are cold (bdelta = -8).
__device__ __forceinline__ float softplus_fast(float x) {
    if (x < -4.f) return __expf(x);
    return (x > 0.f) ? (x + log1pf(__expf(-x))) : log1pf(__expf(x));
}
__device__ __forceinline__ float silu_fast(float v) {
    return v * __fdividef(1.f, 1.f + __expf(-v));
}

// ---------------- f32 -> bf16, 4 elems/thread ----------------
__global__ void cvt_bf16(const float* __restrict__ src, u16* __restrict__ dst, int n4) {
    int i = blockIdx.x * blockDim.x + threadIdx.x;
    if (i >= n4) return;
    const float4 v = reinterpret_cast<const float4*>(src)[i];
    ushort4 o;
    o.x = f2bf(v.x); o.y = f2bf(v.y); o.z = f2bf(v.z); o.w = f2bf(v.w);
    reinterpret_cast<ushort4*>(dst)[i] = o;
}

// ---------------- GEMM: C[M,N] = A[M,K] @ B[N,K]^T  (bf16 in, f32 acc) ----------------
// 2-phase double-buffered pipeline (verified R6 sync structure, unchanged):
// per iter {STAGE(next -> other buf); compute(cur); vmcnt(0); s_barrier}.
// This round: tile-size parameterized, 512 threads / 8 waves.
//   <256,256>: wave grid 2m x 4n, per-wave 128x64, acc[8][4], LDS 128 KB
//   <256,128>: wave grid 4m x 2n, per-wave  64x64, acc[4][4], LDS  96 KB
// XOR-swizzled LDS (both sides), bijective XCD block swizzle.
// EP 0: Cb = bf16(acc + b1)
// EP 1: C  = acc + b1 + b2; Cb = bf16(C)       (fused Wd/Wc dual-out)
// EP 2: Cb = bf16(aux * silu(acc))             (gate)
// EP 3: C  = aux + acc                         (final residual, f32 out)
// EP 4: split N=2*DH: col<DH  -> Cb [row][col]     = bf16(softplus(acc+b1[col]))   (delta)
//                     col>=DH -> Cb2[row][col-DH]  = bf16(acc+b2[col-DH])          (pBv)
__device__ __forceinline__ void gload_lds16(const void* g, void* l) {
    __builtin_amdgcn_global_load_lds(
        (const __attribute__((address_space(1))) void*)g,
        (__attribute__((address_space(3))) void*)l,
        16, 0, 0);
}

template<int EP, bool TWOK, int BM, int BN, int WGM, int WGN>
__global__ __launch_bounds__(512) void gemm_bt(
    const u16* __restrict__ A1, const u16* __restrict__ B1, int K1,
    const u16* __restrict__ A2, const u16* __restrict__ B2, int K2,
    float* __restrict__ C, u16* __restrict__ Cb, u16* __restrict__ Cb2,
    const float* __restrict__ bias, const float* __restrict__ bias2,
    const float* __restrict__ aux,
    int M, int N)
{
    constexpr int FM = BM / WGM / 16;      // fragment rows per wave
    constexpr int FN = BN / WGN / 16;      // fragment cols per wave
    __shared__ u16 As[2][BM*64];
    __shared__ u16 Bs[2][BN*64];
    const int tid = threadIdx.x;

    // XCD-aware bijective block swizzle (nwg % 8 == 0 for all our grids)
    const int nwg = gridDim.x * gridDim.y;
    int wg = blockIdx.y * gridDim.x + blockIdx.x;
    wg = (wg & 7) * (nwg >> 3) + (wg >> 3);
    const int m0 = (wg / gridDim.x) * BM;
    const int n0 = (wg % gridDim.x) * BN;

    const int wave = tid >> 6, lane = tid & 63;
    const int wr = (wave / WGN) * (BM / WGM);
    const int wc = (wave % WGN) * (BN / WGN);
    const int fr = lane & 15, fq = lane >> 4;

    f32x4 acc[FM][FN];
    #pragma unroll
    for (int m = 0; m < FM; m++)
        #pragma unroll
        for (int n = 0; n < FN; n++) acc[m][n] = f32x4{0.f, 0.f, 0.f, 0.f};

    const int nt1 = K1 >> 6;
    const int nt  = TWOK ? nt1 + (K2 >> 6) : nt1;

    auto stage = [&](int t, int buf) {
        const u16* A = A1; const u16* B = B1; int K = K1; int k0 = t << 6;
        if (TWOK && t >= nt1) { A = A2; B = B2; K = K2; k0 = (t - nt1) << 6; }
        #pragma unroll
        for (int i = 0; i < BM/64; ++i) {        // 16B granules, 512 threads
            const int g = i*512 + tid;
            const int r = g >> 3;
            const int ch = (g & 7) ^ (r & 7);    // pre-swizzled source chunk
            gload_lds16(A + (size_t)(m0 + r)*K + (k0 + ch*8), (char*)As[buf] + (size_t)g*16);
        }
        #pragma unroll
        for (int i = 0; i < BN/64; ++i) {
            const int g = i*512 + tid;
            const int r = g >> 3;
            const int ch = (g & 7) ^ (r & 7);
            gload_lds16(B + (size_t)(n0 + r)*K + (k0 + ch*8), (char*)Bs[buf] + (size_t)g*16);
        }
    };

    auto compute = [&](int buf) {
        #pragma unroll
        for (int kk = 0; kk < 2; ++kk) {
            bf16x8 af[FM], bfr[FN];
            #pragma unroll
            for (int m = 0; m < FM; m++) {
                const int r = wr + m*16 + fr;
                af[m] = *reinterpret_cast<const bf16x8*>(
                    (const char*)As[buf] + r*128 + (((kk*4 + fq) ^ (r & 7)) * 16));
            }
            #pragma unroll
            for (int n = 0; n < FN; n++) {
                const int r = wc + n*16 + fr;
                bfr[n] = *reinterpret_cast<const bf16x8*>(
                    (const char*)Bs[buf] + r*128 + (((kk*4 + fq) ^ (r & 7)) * 16));
            }
            #pragma unroll
            for (int m = 0; m < FM; m++)
                #pragma unroll
                for (int n = 0; n < FN; n++)
                    acc[m][n] = __builtin_amdgcn_mfma_f32_16x16x32_bf16(af[m], bfr[n], acc[m][n], 0, 0, 0);
        }
    };

    // prologue: fill buf0
    stage(0, 0);
    asm volatile("s_waitcnt vmcnt(0)" ::: "memory");
    __builtin_amdgcn_s_barrier();
    __builtin_amdgcn_sched_barrier(0);

    int cur = 0;
    for (int t = 0; t < nt; ++t) {
        if (t + 1 < nt) stage(t + 1, cur ^ 1);   // issue next-tile loads first
        compute(cur);                            // MFMAs hide the load latency
        asm volatile("s_waitcnt vmcnt(0)" ::: "memory");   // next tile landed
        __builtin_amdgcn_s_barrier();            // all waves done with cur + loads landed
        __builtin_amdgcn_sched_barrier(0);
        cur ^= 1;
    }

    #pragma unroll
    for (int m = 0; m < FM; m++) {
        #pragma unroll
        for (int n = 0; n < FN; n++) {
            const int col = n0 + wc + n*16 + fr;
            float bv = 0.f;
            if constexpr (EP != 4) {
                if (bias)  bv += bias[col];
                if (bias2) bv += bias2[col];
            }
            #pragma unroll
            for (int j = 0; j < 4; j++) {
                const int row = m0 + wr + m*16 + fq*4 + j;   // C row = (lane>>4)*4+reg
                const size_t idx = (size_t)row * N + col;
                float v = acc[m][n][j] + bv;
                if constexpr (EP == 0) {
                    Cb[idx] = f2bf(v);
                } else if constexpr (EP == 1) {
                    C[idx] = v;
                    Cb[idx] = f2bf(v);
                } else if constexpr (EP == 2) {
                    Cb[idx] = f2bf(aux[idx] * silu_fast(v));
                } else if constexpr (EP == 3) {
                    C[idx] = aux[idx] + v;
                } else {   // EP 4: merged delta | pBv (block-uniform split at col==DH)
                    if (col < DH) {
                        Cb [(size_t)row*DH + col]        = f2bf(softplus_fast(v + bias[col]));
                    } else {
                        Cb2[(size_t)row*DH + (col - DH)] = f2bf(v + bias2[col - DH]);
                    }
                }
            }
        }
    }
}

// ---------------- depthwise conv3 (pad 1, per seq of 4096) + silu, bf16x8 ----------------
__global__ void conv_silu8(const u16* __restrict__ x1, const float* __restrict__ cw,
                           const float* __restrict__ cb, u16* __restrict__ xab) {
    int t = blockIdx.x * blockDim.x + threadIdx.x;   // over Mp*DMODEL/8
    int c8  = t & (DMODEL/8 - 1);
    int row = t >> 7;
    int l = row & (SEQ - 1);
    const int c0 = c8 * 8;
    const size_t i0 = (size_t)row * DMODEL + c0;
    bf16x8 v0 = *reinterpret_cast<const bf16x8*>(x1 + i0);
    bf16x8 vm = {}; if (l > 0)       vm = *reinterpret_cast<const bf16x8*>(x1 + i0 - DMODEL);
    bf16x8 vp = {}; if (l < SEQ - 1) vp = *reinterpret_cast<const bf16x8*>(x1 + i0 + DMODEL);
    if (l == 0)       vm = bf16x8{};
    if (l == SEQ - 1) vp = bf16x8{};
    bf16x8 o;
    #pragma unroll
    for (int j = 0; j < 8; ++j) {
        const int c = c0 + j;
        float v = cw[c*3+0]*bf2f((u16)vm[j]) + cw[c*3+1]*bf2f((u16)v0[j])
                + cw[c*3+2]*bf2f((u16)vp[j]) + cb[c];
        o[j] = (short)f2bf(silu_fast(v));
    }
    *reinterpret_cast<bf16x8*>(xab + i0) = o;
}

// ---------------- SSM chunked scan (batch in grid.z) ----------------
__global__ void scan_chunks(const u16* __restrict__ delta, const u16* __restrict__ pBv,
                            const float* __restrict__ Avec,
                            float* __restrict__ cA, float* __restrict__ cB) {
    const int c = blockIdx.x * blockDim.x + threadIdx.x;
    const int q = blockIdx.y;
    const int b = blockIdx.z;
    const float Ac = Avec[c];
    float hA = 1.f, hB = 0.f;
    size_t base = ((size_t)b*SEQ + q*CHUNK)*DH + c;
    for (int j = 0; j < CHUNK; ++j) {
        float d = bf2f(delta[base]);
        float Abar = __expf(d * Ac);
        hA *= Abar;
        hB = Abar*hB + d * bf2f(pBv[base]);
        base += DH;
    }
    size_t o = ((size_t)b*NCHUNK + q)*DH + c;
    cA[o] = hA; cB[o] = hB;
}

__global__ void scan_prefix(const float* __restrict__ cA, const float* __restrict__ cB,
                            float* __restrict__ cH) {
    const int t = blockIdx.x * blockDim.x + threadIdx.x;   // nb*DH
    const int b = t >> 11;          // /DH
    const int c = t & (DH - 1);
    float h = 0.f;
    size_t o = ((size_t)b*NCHUNK)*DH + c;
    float a = cA[o], bb = cB[o];
    for (int q = 0; q < NCHUNK; ++q) {
        const size_t on = o + DH;
        float a2 = 0.f, b2 = 0.f;
        if (q + 1 < NCHUNK) { a2 = cA[on]; b2 = cB[on]; }   // prefetch next
        cH[o] = h;                   // state BEFORE chunk q
        h = a*h + bb;
        a = a2; bb = b2; o = on;
    }
}

__global__ void scan_apply(const u16* __restrict__ delta, const u16* __restrict__ pBv,
                           const float* __restrict__ Avec, const float* __restrict__ cH,
                           u16* __restrict__ hstb) {
    const int c = blockIdx.x * blockDim.x + threadIdx.x;
    const int q = blockIdx.y;
    const int b = blockIdx.z;
    const float Ac = Avec[c];
    float h = cH[((size_t)b*NCHUNK + q)*DH + c];
    size_t base = ((size_t)b*SEQ + q*CHUNK)*DH + c;
    for (int j = 0; j < CHUNK; ++j) {
        float d = bf2f(delta[base]);
        float Abar = __expf(d * Ac);
        h = Abar*h + d * bf2f(pBv[base]);
        hstb[base] = f2bf(h);
        base += DH;
    }
}

// ---------------- host ----------------
extern "C" void kernel_launch(void* const* d_in, const int* in_sizes, int n_in,
                              void* d_out, int out_size, void* d_ws, size_t ws_size,
                              hipStream_t stream) {
    const float* x      = (const float*)d_in[0];
    const float* W1     = (const float*)d_in[1];
    const float* conv_w = (const float*)d_in[2];
    const float* conv_b = (const float*)d_in[3];
    const float* Avec   = (const float*)d_in[4];
    const float* Wb     = (const float*)d_in[5];
    const float* bb     = (const float*)d_in[6];
    const float* Wc     = (const float*)d_in[7];
    const float* bc     = (const float*)d_in[8];
    const float* Wd     = (const float*)d_in[9];
    const float* bd     = (const float*)d_in[10];
    const float* Wdelta = (const float*)d_in[11];
    const float* bdelta = (const float*)d_in[12];
    const float* W2     = (const float*)d_in[13];
    const float* Wlast  = (const float*)d_in[14];
    float* out = (float*)d_out;
    (void)in_sizes; (void)n_in; (void)out_size;

    // ---- layout (aliased by lifetime); prefer full-batch (1 pass), else 2 passes ----
    struct Ptrs {
        u16 *sW;                  // 8 MB weight slot (Wdelta|Wb merged, or Wd|Wc, or single)
        float *cA, *cB, *cH;
        u16 *xb, *x1b, *xab, *delta, *pBv, *ossb, *hstb, *zb;
        float *oss;
        size_t total;
    };
    auto layout = [&](int passes) -> Ptrs {
        Ptrs P{};
        const size_t Mp = MROWS / passes;
        const int nb = BATCH / passes;
        size_t off = 0;
        auto al = [&](size_t bytes) -> char* {
            char* p = (char*)d_ws + off; off += (bytes + 255) & ~(size_t)255; return p;
        };
        P.sW  = (u16*)al((size_t)2*DH*DMODEL*2);      // 8 MB
        P.cA  = (float*)al((size_t)nb*NCHUNK*DH*4);
        P.cB  = (float*)al((size_t)nb*NCHUNK*DH*4);
        P.cH  = (float*)al((size_t)nb*NCHUNK*DH*4);
        char* RA = al(Mp*DMODEL*2);                   // xb -> ossb
        char* RB = al(Mp*DMODEL*2);                   // x1b -> zb
        char* RC = al(Mp*DMODEL*2);                   // xab
        char* RD = al(Mp*DH*2);                       // delta -> oss (f32 Mp*DMODEL*4, same bytes)
        char* RE = al(Mp*DH*2);                       // pBv
        char* RF = al(Mp*DH*2);                       // hstb
        P.xb    = (u16*)RA; P.ossb = (u16*)RA;
        P.x1b   = (u16*)RB; P.zb   = (u16*)RB;
        P.xab   = (u16*)RC;
        P.delta = (u16*)RD; P.oss  = (float*)RD;
        P.pBv   = (u16*)RE;
        P.hstb  = (u16*)RF;
        P.total = off;
        return P;
    };

    int passes = (ws_size >= layout(1).total) ? 1 : 2;
    Ptrs P = layout(passes);
    if (ws_size < P.total) return;   // clean diagnostic fail instead of fault
    const int Mp = MROWS / passes;
    const int nb = BATCH / passes;

    const dim3 blk(256);
    const dim3 blkG(512);
    auto cvt = [&](const float* s, u16* d, size_t n) {
        int n4 = (int)(n / 4);
        cvt_bf16<<<dim3((n4 + 255)/256), blk, 0, stream>>>(s, d, n4);
    };
    const dim3 gD (DMODEL/128, Mp/256);   // <256,128>: 256 blocks (1-pass)
    const dim3 gDB(2*DH/256,   Mp/256);   // <256,256>: 512 blocks (merged delta|pBv)
    u16* sW2 = P.sW + (size_t)DH*DMODEL;  // second half of weight slot

    for (int p = 0; p < passes; ++p) {
        const float* x_p  = x  + (size_t)p*Mp*DMODEL;
        float*      out_p = out + (size_t)p*Mp*DMODEL;

        cvt(x_p, P.xb, (size_t)Mp*DMODEL);
        // x1 = x @ W1^T
        cvt(W1, P.sW, (size_t)DMODEL*DMODEL);
        gemm_bt<0,false,256,128,4,2><<<gD, blkG, 0, stream>>>(P.xb, P.sW, DMODEL, nullptr, nullptr, 0,
                                                 nullptr, P.x1b, nullptr, nullptr, nullptr, nullptr, Mp, DMODEL);
        // xa = silu(conv3(x1))
        conv_silu8<<<dim3(Mp*DMODEL/8/256), blk, 0, stream>>>(P.x1b, conv_w, conv_b, P.xab);
        // merged: delta = softplus(xa@Wdelta^T + bdelta), pBv = xa@Wb^T + bb  (one N=4096 GEMM)
        cvt(Wdelta, P.sW, (size_t)DH*DMODEL);
        cvt(Wb,     sW2,  (size_t)DH*DMODEL);
        gemm_bt<4,false,256,256,2,4><<<gDB, blkG, 0, stream>>>(P.xab, P.sW, DMODEL, nullptr, nullptr, 0,
                                                  nullptr, P.delta, P.pBv, bdelta, bb, nullptr, Mp, 2*DH);
        // chunked scan -> h_st (bf16)
        scan_chunks<<<dim3(DH/256, NCHUNK, nb), blk, 0, stream>>>(P.delta, P.pBv, Avec, P.cA, P.cB);
        scan_prefix<<<dim3(nb*DH/256), blk, 0, stream>>>(P.cA, P.cB, P.cH);
        scan_apply <<<dim3(DH/256, NCHUNK, nb), blk, 0, stream>>>(P.delta, P.pBv, Avec, P.cH, P.hstb);
        // oss = xa @ Wd^T + h_st @ Wc^T + (bd+bc)   (f32 + bf16 dual out, fused two-K GEMM)
        cvt(Wd, P.sW, (size_t)DMODEL*DMODEL);
        cvt(Wc, sW2,  (size_t)DMODEL*DH);
        gemm_bt<1,true,256,128,4,2><<<gD, blkG, 0, stream>>>(P.xab, P.sW, DMODEL, P.hstb, sW2, DH,
                                                P.oss, P.ossb, nullptr, bd, bc, nullptr, Mp, DMODEL);
        // z = oss * silu(oss @ W2^T)
        cvt(W2, P.sW, (size_t)DMODEL*DMODEL);
        gemm_bt<2,false,256,128,4,2><<<gD, blkG, 0, stream>>>(P.ossb, P.sW, DMODEL, nullptr, nullptr, 0,
                                                 nullptr, P.zb, nullptr, nullptr, nullptr, P.oss, Mp, DMODEL);
        // out = oss + z @ Wlast^T
        cvt(Wlast, P.sW, (size_t)DMODEL*DMODEL);
        gemm_bt<3,false,256,128,4,2><<<gD, blkG, 0, stream>>>(P.zb, P.sW, DMODEL, nullptr, nullptr, 0,
                                                 out_p, nullptr, nullptr, nullptr, nullptr, P.oss, Mp, DMODEL);
    }
}

// Round 8
// 356.246 us; speedup vs baseline: 1.0651x; 1.0651x over previous
//
#include <hip/hip_runtime.h>
#include <cstdint>
#include <cstddef>

#define DMODEL 1024
#define DH 2048
#define BATCH 2
#define SEQ 4096
#define MROWS (BATCH*SEQ)    // 8192
#define CHUNK 64
#define NCHUNK (SEQ/CHUNK)   // 64

typedef unsigned short u16;
typedef __attribute__((ext_vector_type(8))) short bf16x8;
typedef __attribute__((ext_vector_type(4))) float f32x4;

__device__ __forceinline__ u16 f2bf(float f) {
    union { float f; unsigned u; } v; v.f = f;
    unsigned r = v.u + 0x7FFFu + ((v.u >> 16) & 1u);
    return (u16)(r >> 16);
}
__device__ __forceinline__ float bf2f(u16 h) {
    union { unsigned u; float f; } v; v.u = ((unsigned)h) << 16; return v.f;
}

// fast softplus: for x < -4, softplus(x) = log1p(e^x) ≈ e^x (rel err ≤ e^-4/2 ≈ 0.9%,
// typical x≈-8 → 1.7e-4). Exact branches are cold (bdelta = -8).
__device__ __forceinline__ float softplus_fast(float x) {
    if (x < -4.f) return __expf(x);
    return (x > 0.f) ? (x + log1pf(__expf(-x))) : log1pf(__expf(x));
}
__device__ __forceinline__ float silu_fast(float v) {
    return v * __fdividef(1.f, 1.f + __expf(-v));
}

// ---------------- f32 -> bf16, 4 elems/thread ----------------
__global__ void cvt_bf16(const float* __restrict__ src, u16* __restrict__ dst, int n4) {
    int i = blockIdx.x * blockDim.x + threadIdx.x;
    if (i >= n4) return;
    const float4 v = reinterpret_cast<const float4*>(src)[i];
    ushort4 o;
    o.x = f2bf(v.x); o.y = f2bf(v.y); o.z = f2bf(v.z); o.w = f2bf(v.w);
    reinterpret_cast<ushort4*>(dst)[i] = o;
}

// ---------------- GEMM: C[M,N] = A[M,K] @ B[N,K]^T  (bf16 in, f32 acc) ----------------
// 128x128 tile, BK=64, 256 thr (2 blocks/CU @ 64 KB LDS), width-16 global_load_lds,
// XOR-swizzled LDS (both sides, rule 21), bijective XCD block swizzle.
// DEPTH-2 counted-vmcnt pipeline (T4): tiles t and t+1 always in flight; per iter
// {vmcnt(8) [cur landed, next still flying] -> barrier -> compute(cur) -> barrier
//  -> stage(t+2 -> cur)}. Loads get a full extra iteration to land.
// EP 0: Cb = bf16(acc + b1)
// EP 1: C  = acc + b1 + b2; Cb = bf16(C)       (fused Wd/Wc dual-out)
// EP 2: Cb = bf16(aux * silu(acc))             (gate)
// EP 3: C  = aux + acc                         (final residual, f32 out)
// EP 4: split N=2*DH: col<DH  -> Cb [row][col]     = bf16(softplus(acc+b1[col]))   (delta)
//                     col>=DH -> Cb2[row][col-DH]  = bf16(acc+b2[col-DH])          (pBv)
__device__ __forceinline__ void gload_lds16(const void* g, void* l) {
    __builtin_amdgcn_global_load_lds(
        (const __attribute__((address_space(1))) void*)g,
        (__attribute__((address_space(3))) void*)l,
        16, 0, 0);
}

template<int EP, bool TWOK>
__global__ __launch_bounds__(256) void gemm_bt(
    const u16* __restrict__ A1, const u16* __restrict__ B1, int K1,
    const u16* __restrict__ A2, const u16* __restrict__ B2, int K2,
    float* __restrict__ C, u16* __restrict__ Cb, u16* __restrict__ Cb2,
    const float* __restrict__ bias, const float* __restrict__ bias2,
    const float* __restrict__ aux,
    int M, int N)
{
    __shared__ u16 As[2][128*64];   // 2 x 16 KB
    __shared__ u16 Bs[2][128*64];   // 2 x 16 KB  (64 KB total -> 2 blocks/CU)
    const int tid = threadIdx.x;

    // XCD-aware bijective block swizzle (nwg % 8 == 0 for all our grids)
    const int nwg = gridDim.x * gridDim.y;
    int wg = blockIdx.y * gridDim.x + blockIdx.x;
    wg = (wg & 7) * (nwg >> 3) + (wg >> 3);
    const int m0 = (wg / gridDim.x) * 128;
    const int n0 = (wg % gridDim.x) * 128;

    const int wave = tid >> 6, lane = tid & 63;
    const int wr = (wave >> 1) * 64;     // 2x2 wave grid, 64x64 per wave
    const int wc = (wave & 1) * 64;
    const int fr = lane & 15, fq = lane >> 4;

    f32x4 acc[4][4];
    #pragma unroll
    for (int m = 0; m < 4; m++)
        #pragma unroll
        for (int n = 0; n < 4; n++) acc[m][n] = f32x4{0.f, 0.f, 0.f, 0.f};

    const int nt1 = K1 >> 6;
    const int nt  = TWOK ? nt1 + (K2 >> 6) : nt1;

    auto stage = [&](int t, int buf) {
        const u16* A = A1; const u16* B = B1; int K = K1; int k0 = t << 6;
        if (TWOK && t >= nt1) { A = A2; B = B2; K = K2; k0 = (t - nt1) << 6; }
        #pragma unroll
        for (int i = 0; i < 4; ++i) {            // 1024 granules of 16B per matrix
            const int g = i*256 + tid;
            const int r = g >> 3;                // tile row
            const int ch = (g & 7) ^ (r & 7);    // pre-swizzled source chunk
            gload_lds16(A + (size_t)(m0 + r)*K + (k0 + ch*8), (char*)As[buf] + (size_t)g*16);
            gload_lds16(B + (size_t)(n0 + r)*K + (k0 + ch*8), (char*)Bs[buf] + (size_t)g*16);
        }
    };

    auto compute = [&](int buf) {
        #pragma unroll
        for (int kk = 0; kk < 2; ++kk) {
            bf16x8 af[4], bfr[4];
            #pragma unroll
            for (int m = 0; m < 4; m++) {
                const int r = wr + m*16 + fr;
                af[m] = *reinterpret_cast<const bf16x8*>(
                    (const char*)As[buf] + r*128 + (((kk*4 + fq) ^ (r & 7)) * 16));
            }
            #pragma unroll
            for (int n = 0; n < 4; n++) {
                const int r = wc + n*16 + fr;
                bfr[n] = *reinterpret_cast<const bf16x8*>(
                    (const char*)Bs[buf] + r*128 + (((kk*4 + fq) ^ (r & 7)) * 16));
            }
            #pragma unroll
            for (int m = 0; m < 4; m++)
                #pragma unroll
                for (int n = 0; n < 4; n++)
                    acc[m][n] = __builtin_amdgcn_mfma_f32_16x16x32_bf16(af[m], bfr[n], acc[m][n], 0, 0, 0);
        }
    };

    // prologue: stage tiles 0 and 1 (8 loads/thread each; up to 16 in flight)
    stage(0, 0);
    if (nt > 1) stage(1, 1);

    int cur = 0;
    for (int t = 0; t < nt; ++t) {
        // wait for CUR tile's loads only; next tile's 8 stay in flight across the barrier
        if (t < nt - 1) { asm volatile("s_waitcnt vmcnt(8)" ::: "memory"); }
        else            { asm volatile("s_waitcnt vmcnt(0)" ::: "memory"); }
        __builtin_amdgcn_s_barrier();            // all waves' cur-portions landed
        __builtin_amdgcn_sched_barrier(0);
        compute(cur);
        __builtin_amdgcn_s_barrier();            // all waves done reading cur
        __builtin_amdgcn_sched_barrier(0);
        if (t + 2 < nt) stage(t + 2, cur);       // refill the just-freed buffer
        cur ^= 1;
    }

    #pragma unroll
    for (int m = 0; m < 4; m++) {
        #pragma unroll
        for (int n = 0; n < 4; n++) {
            const int col = n0 + wc + n*16 + fr;
            float bv = 0.f;
            if constexpr (EP != 4) {
                if (bias)  bv += bias[col];
                if (bias2) bv += bias2[col];
            }
            #pragma unroll
            for (int j = 0; j < 4; j++) {
                const int row = m0 + wr + m*16 + fq*4 + j;   // C row = (lane>>4)*4+reg
                const size_t idx = (size_t)row * N + col;
                float v = acc[m][n][j] + bv;
                if constexpr (EP == 0) {
                    Cb[idx] = f2bf(v);
                } else if constexpr (EP == 1) {
                    C[idx] = v;
                    Cb[idx] = f2bf(v);
                } else if constexpr (EP == 2) {
                    Cb[idx] = f2bf(aux[idx] * silu_fast(v));
                } else if constexpr (EP == 3) {
                    C[idx] = aux[idx] + v;
                } else {   // EP 4: merged delta | pBv (block-uniform split at col==DH)
                    if (col < DH) {
                        Cb [(size_t)row*DH + col]        = f2bf(softplus_fast(v + bias[col]));
                    } else {
                        Cb2[(size_t)row*DH + (col - DH)] = f2bf(v + bias2[col - DH]);
                    }
                }
            }
        }
    }
}

// ---------------- depthwise conv3 (pad 1, per seq of 4096) + silu, bf16x8 ----------------
__global__ void conv_silu8(const u16* __restrict__ x1, const float* __restrict__ cw,
                           const float* __restrict__ cb, u16* __restrict__ xab) {
    int t = blockIdx.x * blockDim.x + threadIdx.x;   // over Mp*DMODEL/8
    int c8  = t & (DMODEL/8 - 1);
    int row = t >> 7;
    int l = row & (SEQ - 1);
    const int c0 = c8 * 8;
    const size_t i0 = (size_t)row * DMODEL + c0;
    bf16x8 v0 = *reinterpret_cast<const bf16x8*>(x1 + i0);
    bf16x8 vm = {}; if (l > 0)       vm = *reinterpret_cast<const bf16x8*>(x1 + i0 - DMODEL);
    bf16x8 vp = {}; if (l < SEQ - 1) vp = *reinterpret_cast<const bf16x8*>(x1 + i0 + DMODEL);
    if (l == 0)       vm = bf16x8{};
    if (l == SEQ - 1) vp = bf16x8{};
    bf16x8 o;
    #pragma unroll
    for (int j = 0; j < 8; ++j) {
        const int c = c0 + j;
        float v = cw[c*3+0]*bf2f((u16)vm[j]) + cw[c*3+1]*bf2f((u16)v0[j])
                + cw[c*3+2]*bf2f((u16)vp[j]) + cb[c];
        o[j] = (short)f2bf(silu_fast(v));
    }
    *reinterpret_cast<bf16x8*>(xab + i0) = o;
}

// ---------------- SSM chunked scan (batch in grid.z) ----------------
__global__ void scan_chunks(const u16* __restrict__ delta, const u16* __restrict__ pBv,
                            const float* __restrict__ Avec,
                            float* __restrict__ cA, float* __restrict__ cB) {
    const int c = blockIdx.x * blockDim.x + threadIdx.x;
    const int q = blockIdx.y;
    const int b = blockIdx.z;
    const float Ac = Avec[c];
    float hA = 1.f, hB = 0.f;
    size_t base = ((size_t)b*SEQ + q*CHUNK)*DH + c;
    for (int j = 0; j < CHUNK; ++j) {
        float d = bf2f(delta[base]);
        float Abar = __expf(d * Ac);
        hA *= Abar;
        hB = Abar*hB + d * bf2f(pBv[base]);
        base += DH;
    }
    size_t o = ((size_t)b*NCHUNK + q)*DH + c;
    cA[o] = hA; cB[o] = hB;
}

__global__ void scan_prefix(const float* __restrict__ cA, const float* __restrict__ cB,
                            float* __restrict__ cH) {
    const int t = blockIdx.x * blockDim.x + threadIdx.x;   // nb*DH
    const int b = t >> 11;          // /DH
    const int c = t & (DH - 1);
    float h = 0.f;
    size_t o = ((size_t)b*NCHUNK)*DH + c;
    float a = cA[o], bb = cB[o];
    for (int q = 0; q < NCHUNK; ++q) {
        const size_t on = o + DH;
        float a2 = 0.f, b2 = 0.f;
        if (q + 1 < NCHUNK) { a2 = cA[on]; b2 = cB[on]; }   // prefetch next
        cH[o] = h;                   // state BEFORE chunk q
        h = a*h + bb;
        a = a2; bb = b2; o = on;
    }
}

__global__ void scan_apply(const u16* __restrict__ delta, const u16* __restrict__ pBv,
                           const float* __restrict__ Avec, const float* __restrict__ cH,
                           u16* __restrict__ hstb) {
    const int c = blockIdx.x * blockDim.x + threadIdx.x;
    const int q = blockIdx.y;
    const int b = blockIdx.z;
    const float Ac = Avec[c];
    float h = cH[((size_t)b*NCHUNK + q)*DH + c];
    size_t base = ((size_t)b*SEQ + q*CHUNK)*DH + c;
    for (int j = 0; j < CHUNK; ++j) {
        float d = bf2f(delta[base]);
        float Abar = __expf(d * Ac);
        h = Abar*h + d * bf2f(pBv[base]);
        hstb[base] = f2bf(h);
        base += DH;
    }
}

// ---------------- host ----------------
extern "C" void kernel_launch(void* const* d_in, const int* in_sizes, int n_in,
                              void* d_out, int out_size, void* d_ws, size_t ws_size,
                              hipStream_t stream) {
    const float* x      = (const float*)d_in[0];
    const float* W1     = (const float*)d_in[1];
    const float* conv_w = (const float*)d_in[2];
    const float* conv_b = (const float*)d_in[3];
    const float* Avec   = (const float*)d_in[4];
    const float* Wb     = (const float*)d_in[5];
    const float* bb     = (const float*)d_in[6];
    const float* Wc     = (const float*)d_in[7];
    const float* bc     = (const float*)d_in[8];
    const float* Wd     = (const float*)d_in[9];
    const float* bd     = (const float*)d_in[10];
    const float* Wdelta = (const float*)d_in[11];
    const float* bdelta = (const float*)d_in[12];
    const float* W2     = (const float*)d_in[13];
    const float* Wlast  = (const float*)d_in[14];
    float* out = (float*)d_out;
    (void)in_sizes; (void)n_in; (void)out_size;

    // ---- layout (aliased by lifetime); prefer full-batch (1 pass), else 2 passes ----
    struct Ptrs {
        u16 *sW;                  // 8 MB weight slot (Wdelta|Wb merged, or Wd|Wc, or single)
        float *cA, *cB, *cH;
        u16 *xb, *x1b, *xab, *delta, *pBv, *ossb, *hstb, *zb;
        float *oss;
        size_t total;
    };
    auto layout = [&](int passes) -> Ptrs {
        Ptrs P{};
        const size_t Mp = MROWS / passes;
        const int nb = BATCH / passes;
        size_t off = 0;
        auto al = [&](size_t bytes) -> char* {
            char* p = (char*)d_ws + off; off += (bytes + 255) & ~(size_t)255; return p;
        };
        P.sW  = (u16*)al((size_t)2*DH*DMODEL*2);      // 8 MB
        P.cA  = (float*)al((size_t)nb*NCHUNK*DH*4);
        P.cB  = (float*)al((size_t)nb*NCHUNK*DH*4);
        P.cH  = (float*)al((size_t)nb*NCHUNK*DH*4);
        char* RA = al(Mp*DMODEL*2);                   // xb -> ossb
        char* RB = al(Mp*DMODEL*2);                   // x1b -> zb
        char* RC = al(Mp*DMODEL*2);                   // xab
        char* RD = al(Mp*DH*2);                       // delta -> oss (f32 Mp*DMODEL*4, same bytes)
        char* RE = al(Mp*DH*2);                       // pBv
        char* RF = al(Mp*DH*2);                       // hstb
        P.xb    = (u16*)RA; P.ossb = (u16*)RA;
        P.x1b   = (u16*)RB; P.zb   = (u16*)RB;
        P.xab   = (u16*)RC;
        P.delta = (u16*)RD; P.oss  = (float*)RD;
        P.pBv   = (u16*)RE;
        P.hstb  = (u16*)RF;
        P.total = off;
        return P;
    };

    int passes = (ws_size >= layout(1).total) ? 1 : 2;
    Ptrs P = layout(passes);
    if (ws_size < P.total) return;   // clean diagnostic fail instead of fault
    const int Mp = MROWS / passes;
    const int nb = BATCH / passes;

    const dim3 blk(256);
    auto cvt = [&](const float* s, u16* d, size_t n) {
        int n4 = (int)(n / 4);
        cvt_bf16<<<dim3((n4 + 255)/256), blk, 0, stream>>>(s, d, n4);
    };
    const dim3 gD (DMODEL/128, Mp/128);   // 512 blocks (1-pass)
    const dim3 gDB(2*DH/128,   Mp/128);   // 2048 blocks (merged delta|pBv)
    u16* sW2 = P.sW + (size_t)DH*DMODEL;  // second half of weight slot

    for (int p = 0; p < passes; ++p) {
        const float* x_p  = x  + (size_t)p*Mp*DMODEL;
        float*      out_p = out + (size_t)p*Mp*DMODEL;

        cvt(x_p, P.xb, (size_t)Mp*DMODEL);
        // x1 = x @ W1^T
        cvt(W1, P.sW, (size_t)DMODEL*DMODEL);
        gemm_bt<0,false><<<gD, blk, 0, stream>>>(P.xb, P.sW, DMODEL, nullptr, nullptr, 0,
                                                 nullptr, P.x1b, nullptr, nullptr, nullptr, nullptr, Mp, DMODEL);
        // xa = silu(conv3(x1))
        conv_silu8<<<dim3(Mp*DMODEL/8/256), blk, 0, stream>>>(P.x1b, conv_w, conv_b, P.xab);
        // merged: delta = softplus(xa@Wdelta^T + bdelta), pBv = xa@Wb^T + bb  (one N=4096 GEMM)
        cvt(Wdelta, P.sW, (size_t)DH*DMODEL);
        cvt(Wb,     sW2,  (size_t)DH*DMODEL);
        gemm_bt<4,false><<<gDB, blk, 0, stream>>>(P.xab, P.sW, DMODEL, nullptr, nullptr, 0,
                                                  nullptr, P.delta, P.pBv, bdelta, bb, nullptr, Mp, 2*DH);
        // chunked scan -> h_st (bf16)
        scan_chunks<<<dim3(DH/256, NCHUNK, nb), blk, 0, stream>>>(P.delta, P.pBv, Avec, P.cA, P.cB);
        scan_prefix<<<dim3(nb*DH/256), blk, 0, stream>>>(P.cA, P.cB, P.cH);
        scan_apply <<<dim3(DH/256, NCHUNK, nb), blk, 0, stream>>>(P.delta, P.pBv, Avec, P.cH, P.hstb);
        // oss = xa @ Wd^T + h_st @ Wc^T + (bd+bc)   (f32 + bf16 dual out, fused two-K GEMM)
        cvt(Wd, P.sW, (size_t)DMODEL*DMODEL);
        cvt(Wc, sW2,  (size_t)DMODEL*DH);
        gemm_bt<1,true><<<gD, blk, 0, stream>>>(P.xab, P.sW, DMODEL, P.hstb, sW2, DH,
                                                P.oss, P.ossb, nullptr, bd, bc, nullptr, Mp, DMODEL);
        // z = oss * silu(oss @ W2^T)
        cvt(W2, P.sW, (size_t)DMODEL*DMODEL);
        gemm_bt<2,false><<<gD, blk, 0, stream>>>(P.ossb, P.sW, DMODEL, nullptr, nullptr, 0,
                                                 nullptr, P.zb, nullptr, nullptr, nullptr, P.oss, Mp, DMODEL);
        // out = oss + z @ Wlast^T
        cvt(Wlast, P.sW, (size_t)DMODEL*DMODEL);
        gemm_bt<3,false><<<gD, blk, 0, stream>>>(P.zb, P.sW, DMODEL, nullptr, nullptr, 0,
                                                 out_p, nullptr, nullptr, nullptr, nullptr, P.oss, Mp, DMODEL);
    }
}